// Round 7
// baseline (919.023 us; speedup 1.0000x reference)
//
#include <hip/hip_runtime.h>
#include <hip/hip_bf16.h>

// VQ-VAE vector quantizer, MI355X (gfx950).
//   inputs : z (8,256,16,16,16) fp32, codebook (1024,256) fp32
//   output : quant (8,256,16,16,16) ++ idx (8,16,16,16) ++ loss (1), fp32 flat
//
// Round 7: barrier-free MFMA filter.
//   Block = 32 tokens, 4 waves; wave w scans code quarter [w*256, w*256+256)
//   for ALL 32 tokens (two 16-token A-groups, 2 MFMA per B-fragment).
//   B fragments read DIRECTLY from global (pre-swizzled fragment order,
//   L2-resident) -> no LDS staging, no __syncthreads in the scan.
//   Filter: per-lane running mins; cross-lane per-token threshold refreshed
//   every 2 tiles (stale thr >= true min -> superset of candidates, no miss;
//   new minima always satisfy s < old_thr + M so they self-append).
//   Candidates merged across waves via LDS atomicAdd (set-deterministic;
//   recheck is lex-min over the set -> deterministic result).
//   Recheck/epilogue: verified round-6 exact np-fp32 pipeline:
//   D = fl(fl(Sz+Se)-2*dot), dot = ascending-d fp32 FMA chain, Sz/Se numpy
//   pairwise order, lex-min (D,k); overflow(>CAP) -> exact full scan.

#define K_CODES 1024
#define DIM 256
#define N_TOK 32768
#define SPATIAL 4096
#define TOK_BLK 32
#define CAP 32
#define MARGIN 1e-3f

typedef __attribute__((ext_vector_type(8))) short short8;
typedef __attribute__((ext_vector_type(4))) float float4v;

// ws layout in floats
#define WS_LOSS 0
#define WS_E2 16      // 1024 floats: Se[k] (np pairwise)
#define WS_EB 2048    // 262144 bf16 = 131072 floats: codebook, B-fragment order

#define O_IDX (8 * DIM * SPATIAL)  // 8388608
#define O_LOSS (O_IDX + N_TOK)     // 8421376

__device__ __forceinline__ float np_pairwise128(const float* x) {
  float r[8];
#pragma unroll
  for (int j = 0; j < 8; j++) r[j] = x[j];
  for (int i = 8; i < 128; i += 8) {
#pragma unroll
    for (int j = 0; j < 8; j++) r[j] = __fadd_rn(r[j], x[i + j]);
  }
  return __fadd_rn(__fadd_rn(__fadd_rn(r[0], r[1]), __fadd_rn(r[2], r[3])),
                   __fadd_rn(__fadd_rn(r[4], r[5]), __fadd_rn(r[6], r[7])));
}

__device__ __forceinline__ short f2bf(float v) {  // RTNE fp32->bf16 bits
  unsigned u = __float_as_uint(v);
  u = (u + 0x7fffu + ((u >> 16) & 1u)) >> 16;
  return (short)u;
}

// prep (verified round 6): Se[k] np-pairwise; codebook -> bf16 fragment order.
// Element (code k, dim d): T=k>>4 (16-code tile), nn=k&15, f=d>>5, q=(d>>3)&3,
// j=d&7 -> short offset ((T*8+f)*64 + (q*16+nn))*8 + j.
__global__ __launch_bounds__(256) void prep_kernel(const float* __restrict__ e,
                                                   float* __restrict__ ws) {
  __shared__ float sq[DIM];
  int k = blockIdx.x, d = threadIdx.x;
  float v = e[k * DIM + d];
  int T = k >> 4, nn = k & 15;
  int f = d >> 5, q = (d >> 3) & 3, j = d & 7;
  int off = ((T * 8 + f) * 64 + (q * 16 + nn)) * 8 + j;
  ((short*)(ws + WS_EB))[off] = f2bf(v);
  sq[d] = __fmul_rn(v, v);
  __syncthreads();
  if (d == 0) {
    ws[WS_E2 + k] = __fadd_rn(np_pairwise128(sq), np_pairwise128(sq + 128));
    if (k == 0) ws[WS_LOSS] = 0.f;
  }
}

__global__ __launch_bounds__(256, 4) void main_kernel(const float* __restrict__ z,
                                                      const float* __restrict__ e,
                                                      float* __restrict__ ws,
                                                      float* __restrict__ out) {
  __shared__ unsigned short cand[TOK_BLK][CAP];
  __shared__ float cands[TOK_BLK][CAP];
  __shared__ int cnt[TOK_BLK];
  __shared__ float wsmin[4][TOK_BLK];
  __shared__ int mini_sh[TOK_BLK];
  __shared__ float el[TOK_BLK][DIM + 1];  // +1 pad: conflict-free column reads
  __shared__ float red[4];

  int tid = threadIdx.x, w = tid >> 6, lane = tid & 63;
  int quad = lane >> 4, nn = lane & 15;
  int n0 = blockIdx.x * TOK_BLK;
  int b = n0 >> 12, s0 = n0 & 4095;
  const float* zb = z + (size_t)b * DIM * SPATIAL + s0;
  const float* Se = ws + WS_E2;

  if (tid < TOK_BLK) cnt[tid] = 0;
  __syncthreads();  // cnt=0 visible before any wave appends

  // ---- A fragments (z -> bf16), two 16-token groups; d = f*32+quad*8+j ----
  short8 A0[8], A1[8];
#pragma unroll
  for (int f = 0; f < 8; f++) {
    short8 a0, a1;
#pragma unroll
    for (int j = 0; j < 8; j++) {
      int d = f * 32 + quad * 8 + j;
      a0[j] = f2bf(zb[(size_t)d * SPATIAL + nn]);
      a1[j] = f2bf(zb[(size_t)d * SPATIAL + 16 + nn]);
    }
    A0[f] = a0;
    A1[f] = a1;
  }

  // ---- Phase C: barrier-free quarter scan (wave w: codes w*256..w*256+255) ----
  const short8* eB8 = (const short8*)(ws + WS_EB);
  float ml0[4] = {3.4e38f, 3.4e38f, 3.4e38f, 3.4e38f};
  float ml1[4] = {3.4e38f, 3.4e38f, 3.4e38f, 3.4e38f};
  float th0[4], th1[4];

  auto refresh = [&]() {
#pragma unroll
    for (int r = 0; r < 4; r++) {
      float m0 = ml0[r];
      m0 = fminf(m0, __shfl_xor(m0, 1, 16));
      m0 = fminf(m0, __shfl_xor(m0, 2, 16));
      m0 = fminf(m0, __shfl_xor(m0, 4, 16));
      m0 = fminf(m0, __shfl_xor(m0, 8, 16));
      th0[r] = m0;
      float m1 = ml1[r];
      m1 = fminf(m1, __shfl_xor(m1, 1, 16));
      m1 = fminf(m1, __shfl_xor(m1, 2, 16));
      m1 = fminf(m1, __shfl_xor(m1, 4, 16));
      m1 = fminf(m1, __shfl_xor(m1, 8, 16));
      th1[r] = m1;
    }
  };

  for (int c = 0; c < 16; c++) {
    int T = w * 16 + c;  // global 16-code tile; k = T*16 + nn
    float4v C0 = {0.f, 0.f, 0.f, 0.f}, C1 = {0.f, 0.f, 0.f, 0.f};
#pragma unroll
    for (int f = 0; f < 8; f++) {
      short8 Bf = eB8[(size_t)(T * 8 + f) * 64 + lane];  // global_load_dwordx4
      C0 = __builtin_amdgcn_mfma_f32_16x16x32_bf16(A0[f], Bf, C0, 0, 0, 0);
      C1 = __builtin_amdgcn_mfma_f32_16x16x32_bf16(A1[f], Bf, C1, 0, 0, 0);
    }
    float SeK = Se[T * 16 + nn];
    float s0[4], s1[4];
#pragma unroll
    for (int r = 0; r < 4; r++) {
      s0[r] = fmaf(-2.f, C0[r], SeK);
      s1[r] = fmaf(-2.f, C1[r], SeK);
      ml0[r] = fminf(ml0[r], s0[r]);
      ml1[r] = fminf(ml1[r], s1[r]);
    }
    if ((c & 1) == 0) refresh();  // stale thr >= true min: superset, no miss

    bool p0[4], p1[4];
#pragma unroll
    for (int r = 0; r < 4; r++) {
      p0[r] = s0[r] < th0[r] + MARGIN;
      p1[r] = s1[r] < th1[r] + MARGIN;
    }
    if (__ballot(p0[0] | p0[1] | p0[2] | p0[3] | p1[0] | p1[1] | p1[2] | p1[3])) {
#pragma unroll
      for (int g = 0; g < 2; g++) {
#pragma unroll
        for (int r = 0; r < 4; r++) {
          bool pr = g ? p1[r] : p0[r];
          unsigned long long bl = __ballot(pr);
          unsigned grp = (unsigned)((bl >> (quad * 16)) & 0xffffULL);
          if (grp) {
            int t = g * 16 + quad * 4 + r;
            int base = 0;
            if (nn == 0) base = atomicAdd(&cnt[t], __popc(grp));
            base = __shfl(base, quad * 16, 64);
            if (pr) {
              int pos = base + __popc(grp & ((1u << nn) - 1u));
              if (pos < CAP) {
                cand[t][pos] = (unsigned short)(T * 16 + nn);
                cands[t][pos] = g ? s1[r] : s0[r];
              }
            }
          }
        }
      }
    }
  }
  refresh();  // final: exact per-token quarter min
  if (nn == 0) {
#pragma unroll
    for (int r = 0; r < 4; r++) {
      wsmin[w][quad * 4 + r] = th0[r];
      wsmin[w][16 + quad * 4 + r] = th1[r];
    }
  }
  __syncthreads();

  // ---- Phase D: exact recheck; 8 lanes per token ----
  int t = tid >> 3, slot = tid & 7;
  // Sz in EXACT numpy pairwise shape, slot-parallel: slot j owns accumulator
  // r[j]; tree ((r0+r1)+(r2+r3))+((r4+r5)+(r6+r7)) via shfl; blocks added last.
  float res01[2];
#pragma unroll
  for (int blk = 0; blk < 2; blk++) {
    float v0 = zb[(size_t)(blk * 128 + slot) * SPATIAL + t];
    float rj = __fmul_rn(v0, v0);
    for (int i = 1; i < 16; i++) {
      float v = zb[(size_t)(blk * 128 + i * 8 + slot) * SPATIAL + t];
      rj = __fadd_rn(rj, __fmul_rn(v, v));
    }
    float a = __fadd_rn(rj, __shfl_down(rj, 1, 8));
    float bq = __fadd_rn(a, __shfl_down(a, 2, 8));
    res01[blk] = __fadd_rn(bq, __shfl_down(bq, 4, 8));  // valid on slot 0
  }
  float Szn = __fadd_rn(res01[0], res01[1]);
  Szn = __shfl(Szn, lane & ~7, 64);  // broadcast slot0 -> group

  float amin = fminf(fminf(wsmin[0][t], wsmin[1][t]),
                     fminf(wsmin[2][t], wsmin[3][t]));
  int cc = cnt[t];
  float bD = 3.4e38f;
  int bK = 0x7fffffff;
  const float* zp = zb + t;
  if (cc <= CAP) {
    for (int c = slot; c < cc; c += 8) {
      float sv = cands[t][c];
      if (sv >= amin + MARGIN) continue;  // prune spurious stale-thr extras
      int k = cand[t][c];
      const float* er = e + (size_t)k * DIM;
      float acc = 0.f;
      for (int d = 0; d < DIM; d++) acc = fmaf(zp[(size_t)d * SPATIAL], er[d], acc);
      float D = __fsub_rn(__fadd_rn(Szn, Se[k]), __fmul_rn(2.f, acc));
      if (D < bD || (D == bD && k < bK)) { bD = D; bK = k; }
    }
  } else {  // overflow: exact full scan (rare, deterministic)
    for (int k = slot; k < K_CODES; k += 8) {
      const float* er = e + (size_t)k * DIM;
      float acc = 0.f;
      for (int d = 0; d < DIM; d++) acc = fmaf(zp[(size_t)d * SPATIAL], er[d], acc);
      float D = __fsub_rn(__fadd_rn(Szn, Se[k]), __fmul_rn(2.f, acc));
      if (D < bD || (D == bD && k < bK)) { bD = D; bK = k; }
    }
  }
#pragma unroll
  for (int off = 4; off > 0; off >>= 1) {  // lex-min across the 8 slots
    float oD = __shfl_down(bD, off, 8);
    int oK = __shfl_down(bK, off, 8);
    if (oD < bD || (oD == bD && oK < bK)) { bD = oD; bK = oK; }
  }
  if (slot == 0) {
    mini_sh[t] = bK;
    out[O_IDX + n0 + t] = (float)bK;
  }
  __syncthreads();

  // ---- stage selected codebook rows to LDS (coalesced rows) ----
  for (int i = 0; i < TOK_BLK; i++)
    el[i][tid] = e[(size_t)mini_sh[i] * DIM + tid];
  __syncthreads();

  // ---- Phase E: quant store + loss (coalesced along tokens) ----
  float sumsq = 0.f;
  float* op = out + (size_t)b * DIM * SPATIAL + s0;
  for (int i = 0; i < 32; i++) {
    int idx = i * 256 + tid;
    int d = idx >> 5;       // i*8 + (tid>>5)
    int t2 = tid & 31;
    float v = el[t2][d];    // pad -> conflict-free
    float zv = zb[(size_t)d * SPATIAL + t2];
    float df = __fsub_rn(v, zv);
    sumsq = fmaf(df, df, sumsq);
    op[(size_t)d * SPATIAL + t2] = v;  // 128 B contiguous per 32 lanes
  }
#pragma unroll
  for (int o = 32; o > 0; o >>= 1) sumsq += __shfl_down(sumsq, o, 64);
  if (lane == 0) red[w] = sumsq;
  __syncthreads();
  if (tid == 0) atomicAdd(ws + WS_LOSS, red[0] + red[1] + red[2] + red[3]);
}

__global__ void loss_kernel(const float* __restrict__ ws, float* __restrict__ out) {
  out[O_LOSS] = 1.25f * ws[WS_LOSS] / 8388608.f;
}

extern "C" void kernel_launch(void* const* d_in, const int* in_sizes, int n_in,
                              void* d_out, int out_size, void* d_ws, size_t ws_size,
                              hipStream_t stream) {
  const float* z = (const float*)d_in[0];
  const float* e = (const float*)d_in[1];
  float* ws = (float*)d_ws;
  float* out = (float*)d_out;

  prep_kernel<<<K_CODES, 256, 0, stream>>>(e, ws);
  main_kernel<<<N_TOK / TOK_BLK, 256, 0, stream>>>(z, e, ws, out);
  loss_kernel<<<1, 1, 0, stream>>>(ws, out);
}

// Round 8
// 320.260 us; speedup vs baseline: 2.8696x; 2.8696x over previous
//
#include <hip/hip_runtime.h>
#include <hip/hip_bf16.h>

// VQ-VAE vector quantizer, MI355X (gfx950).
//   inputs : z (8,256,16,16,16) fp32, codebook (1024,256) fp32
//   output : quant (8,256,16,16,16) ++ idx (8,16,16,16) ++ loss (1), fp32 flat
//
// Round 8: max-occupancy barrier-free MFMA filter.
//   Block = 16 tokens, 4 waves; wave w scans code quarter [w*256,(w+1)*256)
//   with ONE A-group (16 tokens) -> ~100 VGPR, no spill (R7's failure was
//   (256,4) -> compiler targeted 64 VGPR and spilled A; (256,2) empirically
//   yields 128). Grid = 2048 blocks = 8192 waves = full residency cap.
//   B fragments direct from L2 (pre-swizzled fragment order) — no staging,
//   no barriers in the scan. Filter: per-lane running mins, cross-lane thr
//   refreshed every 2 tiles (stale thr >= true min -> superset, no miss;
//   verified R7). Candidates merged across waves via LDS atomicAdd
//   (set-deterministic; recheck is lex-min -> deterministic).
//   Recheck: verified exact np-fp32 pipeline D = fl(fl(Sz+Se)-2*dot),
//   dot = ascending-d fp32 FMA chain, Sz/Se numpy pairwise order, lex-min
//   (D,k) == np.argmin first occurrence; overflow(>CAP) -> exact full scan.
//   Loss fused via device-scope done-counter (one less launch).

#define K_CODES 1024
#define DIM 256
#define N_TOK 32768
#define SPATIAL 4096
#define TOK_BLK 16
#define CAP 48
#define MARGIN 1e-3f

typedef __attribute__((ext_vector_type(8))) short short8;
typedef __attribute__((ext_vector_type(4))) float float4v;

// ws layout in floats
#define WS_LOSS 0
#define WS_DONE_I 1   // int slot: completed-block counter
#define WS_E2 16      // 1024 floats: Se[k] (np pairwise)
#define WS_EB 2048    // 262144 bf16 = 131072 floats: codebook, B-fragment order

#define O_IDX (8 * DIM * SPATIAL)  // 8388608
#define O_LOSS (O_IDX + N_TOK)     // 8421376
#define N_BLOCKS (N_TOK / TOK_BLK) // 2048

__device__ __forceinline__ short f2bf(float v) {  // RTNE fp32->bf16 bits
  unsigned u = __float_as_uint(v);
  u = (u + 0x7fffu + ((u >> 16) & 1u)) >> 16;
  return (short)u;
}

// prep: coalesced fragment pack + Se (np pairwise, slot-parallel, verified).
// Fragment layout (verified R6/R7): element (code k, dim d): T=k>>4, nn=k&15,
// f=d>>5, q=(d>>3)&3, j=d&7 -> short off ((T*8+f)*64 + (q*16+nn))*8 + j.
__global__ __launch_bounds__(256) void prep_kernel(const float* __restrict__ e,
                                                   float* __restrict__ ws) {
  int T = blockIdx.x, tid = threadIdx.x;
#pragma unroll
  for (int ii = 0; ii < 2; ii++) {
    int idx = ii * 256 + tid;  // 512 short8 fragments per 16-code tile
    int f = idx >> 6, lane = idx & 63;
    int q = lane >> 4, nn = lane & 15;
    const float* src = e + (size_t)(T * 16 + nn) * DIM + f * 32 + q * 8;
    float4 lo = *(const float4*)src;
    float4 hi = *(const float4*)(src + 4);
    unsigned s0 = (unsigned short)f2bf(lo.x) | ((unsigned)(unsigned short)f2bf(lo.y) << 16);
    unsigned s1 = (unsigned short)f2bf(lo.z) | ((unsigned)(unsigned short)f2bf(lo.w) << 16);
    unsigned s2 = (unsigned short)f2bf(hi.x) | ((unsigned)(unsigned short)f2bf(hi.y) << 16);
    unsigned s3 = (unsigned short)f2bf(hi.z) | ((unsigned)(unsigned short)f2bf(hi.w) << 16);
    uint4 p = {s0, s1, s2, s3};
    ((uint4*)(ws + WS_EB))[(T * 8 + f) * 64 + lane] = p;  // coalesced 16B
  }
  if (tid < 128) {  // Se: 8 slots per code, np pairwise (verified R7 form)
    int c8 = tid >> 3, slot = tid & 7;
    int k = T * 16 + c8;
    const float* er = e + (size_t)k * DIM;
    float res01[2];
#pragma unroll
    for (int blk = 0; blk < 2; blk++) {
      float v0 = er[blk * 128 + slot];
      float rj = __fmul_rn(v0, v0);
      for (int i = 1; i < 16; i++) {
        float v = er[blk * 128 + i * 8 + slot];
        rj = __fadd_rn(rj, __fmul_rn(v, v));
      }
      float a = __fadd_rn(rj, __shfl_down(rj, 1, 8));
      float bq = __fadd_rn(a, __shfl_down(a, 2, 8));
      res01[blk] = __fadd_rn(bq, __shfl_down(bq, 4, 8));  // valid on slot 0
    }
    if (slot == 0) ws[WS_E2 + k] = __fadd_rn(res01[0], res01[1]);
  }
  if (T == 0 && tid == 0) {
    ws[WS_LOSS] = 0.f;
    ((int*)ws)[WS_DONE_I] = 0;
  }
}

__global__ __launch_bounds__(256, 2) void main_kernel(const float* __restrict__ z,
                                                      const float* __restrict__ e,
                                                      float* __restrict__ ws,
                                                      float* __restrict__ out) {
  __shared__ unsigned short cand[TOK_BLK][CAP];
  __shared__ float cands[TOK_BLK][CAP];
  __shared__ int cnt[TOK_BLK];
  __shared__ float wsmin[4][TOK_BLK];
  __shared__ int mini_sh[TOK_BLK];
  __shared__ float el[TOK_BLK][DIM + 1];
  __shared__ float red[4];

  int tid = threadIdx.x, w = tid >> 6, lane = tid & 63;
  int quad = lane >> 4, nn = lane & 15;
  int n0 = blockIdx.x * TOK_BLK;
  int b = n0 >> 12, s0 = n0 & 4095;
  const float* zb = z + (size_t)b * DIM * SPATIAL + s0;
  const float* Se = ws + WS_E2;

  if (tid < TOK_BLK) cnt[tid] = 0;
  __syncthreads();  // cnt=0 visible before appends

  // ---- A fragments (z -> bf16): token = nn, dim d = f*32 + quad*8 + j ----
  short8 A[8];
#pragma unroll
  for (int f = 0; f < 8; f++) {
    short8 a;
#pragma unroll
    for (int j = 0; j < 8; j++)
      a[j] = f2bf(zb[(size_t)(f * 32 + quad * 8 + j) * SPATIAL + nn]);
    A[f] = a;
  }

  // ---- Phase C: barrier-free quarter scan (wave w: codes w*256..+255) ----
  const short8* eB8 = (const short8*)(ws + WS_EB);
  float ml[4] = {3.4e38f, 3.4e38f, 3.4e38f, 3.4e38f};
  float th[4];
  auto refresh = [&]() {
#pragma unroll
    for (int r = 0; r < 4; r++) {
      float m = ml[r];
      m = fminf(m, __shfl_xor(m, 1, 16));
      m = fminf(m, __shfl_xor(m, 2, 16));
      m = fminf(m, __shfl_xor(m, 4, 16));
      m = fminf(m, __shfl_xor(m, 8, 16));
      th[r] = m;
    }
  };

  for (int c = 0; c < 16; c++) {
    int T = w * 16 + c;  // k = T*16 + nn
    float4v C = {0.f, 0.f, 0.f, 0.f};
#pragma unroll
    for (int f = 0; f < 8; f++) {
      short8 Bf = eB8[(size_t)(T * 8 + f) * 64 + lane];  // L2-resident
      C = __builtin_amdgcn_mfma_f32_16x16x32_bf16(A[f], Bf, C, 0, 0, 0);
    }
    float SeK = Se[T * 16 + nn];
    float sv[4];
#pragma unroll
    for (int r = 0; r < 4; r++) {
      sv[r] = fmaf(-2.f, C[r], SeK);  // token = quad*4+r, code = nn
      ml[r] = fminf(ml[r], sv[r]);
    }
    if ((c & 1) == 0) refresh();  // stale thr >= true min: superset, no miss

    bool pr[4];
#pragma unroll
    for (int r = 0; r < 4; r++) pr[r] = sv[r] < th[r] + MARGIN;
    if (__ballot(pr[0] | pr[1] | pr[2] | pr[3])) {
#pragma unroll
      for (int r = 0; r < 4; r++) {
        unsigned long long bl = __ballot(pr[r]);
        unsigned grp = (unsigned)((bl >> (quad * 16)) & 0xffffULL);
        if (grp) {
          int t = quad * 4 + r;
          int base = 0;
          if (nn == 0) base = atomicAdd(&cnt[t], __popc(grp));
          base = __shfl(base, quad * 16, 64);
          if (pr[r]) {
            int pos = base + __popc(grp & ((1u << nn) - 1u));
            if (pos < CAP) {
              cand[t][pos] = (unsigned short)(T * 16 + nn);
              cands[t][pos] = sv[r];
            }
          }
        }
      }
    }
  }
  refresh();  // exact quarter min
  if (nn == 0) {
#pragma unroll
    for (int r = 0; r < 4; r++) wsmin[w][quad * 4 + r] = th[r];
  }
  __syncthreads();

  // ---- Phase D: exact recheck; 8 slots per token, tokens 0..15 ----
  if (tid < 128) {
    int t = tid >> 3, slot = tid & 7;
    // Sz in exact numpy pairwise shape, slot-parallel (verified R7)
    float res01[2];
#pragma unroll
    for (int blk = 0; blk < 2; blk++) {
      float v0 = zb[(size_t)(blk * 128 + slot) * SPATIAL + t];
      float rj = __fmul_rn(v0, v0);
      for (int i = 1; i < 16; i++) {
        float v = zb[(size_t)(blk * 128 + i * 8 + slot) * SPATIAL + t];
        rj = __fadd_rn(rj, __fmul_rn(v, v));
      }
      float a = __fadd_rn(rj, __shfl_down(rj, 1, 8));
      float bq = __fadd_rn(a, __shfl_down(a, 2, 8));
      res01[blk] = __fadd_rn(bq, __shfl_down(bq, 4, 8));
    }
    float Szn = __fadd_rn(res01[0], res01[1]);
    Szn = __shfl(Szn, lane & ~7, 64);  // broadcast slot0

    float amin = fminf(fminf(wsmin[0][t], wsmin[1][t]),
                       fminf(wsmin[2][t], wsmin[3][t]));
    int cc = cnt[t];
    float bD = 3.4e38f;
    int bK = 0x7fffffff;
    const float* zp = zb + t;
    if (cc <= CAP) {
      for (int c = slot; c < cc; c += 8) {
        float sv = cands[t][c];
        if (sv >= amin + MARGIN) continue;  // prune stale-thr extras
        int k = cand[t][c];
        const float* er = e + (size_t)k * DIM;
        float acc = 0.f;
        for (int d = 0; d < DIM; d++) acc = fmaf(zp[(size_t)d * SPATIAL], er[d], acc);
        float D = __fsub_rn(__fadd_rn(Szn, Se[k]), __fmul_rn(2.f, acc));
        if (D < bD || (D == bD && k < bK)) { bD = D; bK = k; }
      }
    } else {  // overflow: exact full scan (rare, deterministic)
      for (int k = slot; k < K_CODES; k += 8) {
        const float* er = e + (size_t)k * DIM;
        float acc = 0.f;
        for (int d = 0; d < DIM; d++) acc = fmaf(zp[(size_t)d * SPATIAL], er[d], acc);
        float D = __fsub_rn(__fadd_rn(Szn, Se[k]), __fmul_rn(2.f, acc));
        if (D < bD || (D == bD && k < bK)) { bD = D; bK = k; }
      }
    }
#pragma unroll
    for (int off = 4; off > 0; off >>= 1) {  // lex-min across 8 slots
      float oD = __shfl_down(bD, off, 8);
      int oK = __shfl_down(bK, off, 8);
      if (oD < bD || (oD == bD && oK < bK)) { bD = oD; bK = oK; }
    }
    if (slot == 0) {
      mini_sh[t] = bK;
      out[O_IDX + n0 + t] = (float)bK;
    }
  }
  __syncthreads();

  // ---- stage selected codebook rows (coalesced) ----
#pragma unroll
  for (int i = 0; i < TOK_BLK; i++)
    el[i][tid] = e[(size_t)mini_sh[i] * DIM + tid];
  __syncthreads();

  // ---- Phase E: quant store + fused loss ----
  float sumsq = 0.f;
  float* op = out + (size_t)b * DIM * SPATIAL + s0;
  for (int i = 0; i < 16; i++) {
    int idx = i * 256 + tid;  // 4096 elements
    int d = idx >> 4, t2 = idx & 15;
    float v = el[t2][d];
    float zv = zb[(size_t)d * SPATIAL + t2];
    float df = __fsub_rn(v, zv);
    sumsq = fmaf(df, df, sumsq);
    op[(size_t)d * SPATIAL + t2] = v;  // 64B contiguous per 16 lanes
  }
#pragma unroll
  for (int o = 32; o > 0; o >>= 1) sumsq += __shfl_down(sumsq, o, 64);
  if (lane == 0) red[w] = sumsq;
  __syncthreads();
  if (tid == 0) {
    atomicAdd(ws + WS_LOSS, red[0] + red[1] + red[2] + red[3]);
    __threadfence();  // loss add visible before counter bump
    int done = atomicAdd((int*)ws + WS_DONE_I, 1);
    if (done == N_BLOCKS - 1) {  // last block: all adds complete & visible
      __threadfence();
      float total = atomicAdd(ws + WS_LOSS, 0.f);  // read via atomic path
      out[O_LOSS] = 1.25f * total / 8388608.f;
    }
  }
}

extern "C" void kernel_launch(void* const* d_in, const int* in_sizes, int n_in,
                              void* d_out, int out_size, void* d_ws, size_t ws_size,
                              hipStream_t stream) {
  const float* z = (const float*)d_in[0];
  const float* e = (const float*)d_in[1];
  float* ws = (float*)d_ws;
  float* out = (float*)d_out;

  prep_kernel<<<K_CODES / 16, 256, 0, stream>>>(e, ws);
  main_kernel<<<N_BLOCKS, 256, 0, stream>>>(z, e, ws, out);
}

// Round 9
// 277.240 us; speedup vs baseline: 3.3149x; 1.1552x over previous
//
#include <hip/hip_runtime.h>
#include <hip/hip_bf16.h>

// VQ-VAE vector quantizer, MI355X (gfx950).
//   inputs : z (8,256,16,16,16) fp32, codebook (1024,256) fp32
//   output : quant (8,256,16,16,16) ++ idx (8,16,16,16) ++ loss (1), fp32 flat
//
// Round 9: R8 structure + z staged ONCE to LDS (R8 was bound by 4x scalar
// re-reads of z from HBM: FETCH 151 MB @ 720 GB/s).
//   Block = 16 tokens, 4 waves; wave w scans code quarter [w*256,(w+1)*256).
//   z-tile -> LDS zl[tok][257] (padded pitch; <=2-way banks everywhere) via
//   wide float4 global loads; A-frags, Sz, recheck dots, epilogue all read
//   LDS. B fragments direct from L2 (pre-swizzled fragment order, verified).
//   Filter: per-lane running mins, cross-lane thr refreshed every 2 tiles
//   (stale thr >= true min -> superset, no miss; verified R7/R8). Candidate
//   merge via LDS atomicAdd (set-deterministic; lex-min recheck).
//   Recheck: verified exact np-fp32 pipeline D = fl(fl(Sz+Se)-2*dot),
//   dot = ascending-d fp32 FMA chain, Sz/Se numpy pairwise order, lex-min
//   (D,k) == np.argmin first occurrence; overflow(>CAP) -> exact full scan.
//   Loss fused via device-scope done-counter (verified R8).

#define K_CODES 1024
#define DIM 256
#define N_TOK 32768
#define SPATIAL 4096
#define TOK_BLK 16
#define CAP 48
#define MARGIN 1e-3f
#define ZPITCH 257

typedef __attribute__((ext_vector_type(8))) short short8;
typedef __attribute__((ext_vector_type(4))) float float4v;

// ws layout in floats
#define WS_LOSS 0
#define WS_DONE_I 1   // int slot: completed-block counter
#define WS_E2 16      // 1024 floats: Se[k] (np pairwise)
#define WS_EB 2048    // 262144 bf16 = 131072 floats: codebook, B-fragment order

#define O_IDX (8 * DIM * SPATIAL)  // 8388608
#define O_LOSS (O_IDX + N_TOK)     // 8421376
#define N_BLOCKS (N_TOK / TOK_BLK) // 2048

__device__ __forceinline__ short f2bf(float v) {  // RTNE fp32->bf16 bits
  unsigned u = __float_as_uint(v);
  u = (u + 0x7fffu + ((u >> 16) & 1u)) >> 16;
  return (short)u;
}

// prep (verified R8): coalesced fragment pack + Se (np pairwise).
// Fragment layout: element (code k, dim d): T=k>>4, nn=k&15, f=d>>5,
// q=(d>>3)&3, j=d&7 -> short off ((T*8+f)*64 + (q*16+nn))*8 + j.
__global__ __launch_bounds__(256) void prep_kernel(const float* __restrict__ e,
                                                   float* __restrict__ ws) {
  int T = blockIdx.x, tid = threadIdx.x;
#pragma unroll
  for (int ii = 0; ii < 2; ii++) {
    int idx = ii * 256 + tid;  // 512 short8 fragments per 16-code tile
    int f = idx >> 6, lane = idx & 63;
    int q = lane >> 4, nn = lane & 15;
    const float* src = e + (size_t)(T * 16 + nn) * DIM + f * 32 + q * 8;
    float4 lo = *(const float4*)src;
    float4 hi = *(const float4*)(src + 4);
    unsigned s0 = (unsigned short)f2bf(lo.x) | ((unsigned)(unsigned short)f2bf(lo.y) << 16);
    unsigned s1 = (unsigned short)f2bf(lo.z) | ((unsigned)(unsigned short)f2bf(lo.w) << 16);
    unsigned s2 = (unsigned short)f2bf(hi.x) | ((unsigned)(unsigned short)f2bf(hi.y) << 16);
    unsigned s3 = (unsigned short)f2bf(hi.z) | ((unsigned)(unsigned short)f2bf(hi.w) << 16);
    uint4 p = {s0, s1, s2, s3};
    ((uint4*)(ws + WS_EB))[(T * 8 + f) * 64 + lane] = p;  // coalesced 16B
  }
  if (tid < 128) {  // Se: 8 slots per code, np pairwise (verified)
    int c8 = tid >> 3, slot = tid & 7;
    int k = T * 16 + c8;
    const float* er = e + (size_t)k * DIM;
    float res01[2];
#pragma unroll
    for (int blk = 0; blk < 2; blk++) {
      float v0 = er[blk * 128 + slot];
      float rj = __fmul_rn(v0, v0);
      for (int i = 1; i < 16; i++) {
        float v = er[blk * 128 + i * 8 + slot];
        rj = __fadd_rn(rj, __fmul_rn(v, v));
      }
      float a = __fadd_rn(rj, __shfl_down(rj, 1, 8));
      float bq = __fadd_rn(a, __shfl_down(a, 2, 8));
      res01[blk] = __fadd_rn(bq, __shfl_down(bq, 4, 8));  // valid on slot 0
    }
    if (slot == 0) ws[WS_E2 + k] = __fadd_rn(res01[0], res01[1]);
  }
  if (T == 0 && tid == 0) {
    ws[WS_LOSS] = 0.f;
    ((int*)ws)[WS_DONE_I] = 0;
  }
}

__global__ __launch_bounds__(256, 2) void main_kernel(const float* __restrict__ z,
                                                      const float* __restrict__ e,
                                                      float* __restrict__ ws,
                                                      float* __restrict__ out) {
  __shared__ float zl[TOK_BLK * ZPITCH];       // 16.4 KB: z-tile [tok][d]
  __shared__ float el[TOK_BLK * ZPITCH];       // selected codebook rows
  __shared__ unsigned short cand[TOK_BLK][CAP];
  __shared__ float cands[TOK_BLK][CAP];
  __shared__ int cnt[TOK_BLK];
  __shared__ float wsmin[4][TOK_BLK];
  __shared__ int mini_sh[TOK_BLK];
  __shared__ float red[4];

  int tid = threadIdx.x, w = tid >> 6, lane = tid & 63;
  int quad = lane >> 4, nn = lane & 15;
  int n0 = blockIdx.x * TOK_BLK;
  int b = n0 >> 12, s0 = n0 & 4095;
  const float* zb = z + (size_t)b * DIM * SPATIAL + s0;
  const float* Se = ws + WS_E2;

  if (tid < TOK_BLK) cnt[tid] = 0;

  // ---- stage z-tile once: float4 global loads, transpose into zl[t][d] ----
#pragma unroll
  for (int i = 0; i < 4; i++) {
    int idx = i * 256 + tid;  // 1024 float4 groups: d = idx>>2, g = idx&3
    int d = idx >> 2, g = idx & 3;
    float4 v = *(const float4*)(zb + (size_t)d * SPATIAL + g * 4);
    zl[(4 * g + 0) * ZPITCH + d] = v.x;
    zl[(4 * g + 1) * ZPITCH + d] = v.y;
    zl[(4 * g + 2) * ZPITCH + d] = v.z;
    zl[(4 * g + 3) * ZPITCH + d] = v.w;
  }
  __syncthreads();  // zl ready; cnt=0 visible

  // ---- A fragments (z -> bf16) from LDS: token = nn, d = f*32+quad*8+j ----
  short8 A[8];
#pragma unroll
  for (int f = 0; f < 8; f++) {
    short8 a;
#pragma unroll
    for (int j = 0; j < 8; j++)
      a[j] = f2bf(zl[nn * ZPITCH + f * 32 + quad * 8 + j]);  // contiguous 32B
    A[f] = a;
  }

  // ---- Phase C: barrier-free quarter scan (wave w: codes w*256..+255) ----
  const short8* eB8 = (const short8*)(ws + WS_EB);
  float ml[4] = {3.4e38f, 3.4e38f, 3.4e38f, 3.4e38f};
  float th[4];
  auto refresh = [&]() {
#pragma unroll
    for (int r = 0; r < 4; r++) {
      float m = ml[r];
      m = fminf(m, __shfl_xor(m, 1, 16));
      m = fminf(m, __shfl_xor(m, 2, 16));
      m = fminf(m, __shfl_xor(m, 4, 16));
      m = fminf(m, __shfl_xor(m, 8, 16));
      th[r] = m;
    }
  };

  for (int c = 0; c < 16; c++) {
    int T = w * 16 + c;  // k = T*16 + nn
    float4v C = {0.f, 0.f, 0.f, 0.f};
#pragma unroll
    for (int f = 0; f < 8; f++) {
      short8 Bf = eB8[(size_t)(T * 8 + f) * 64 + lane];  // L2-resident
      C = __builtin_amdgcn_mfma_f32_16x16x32_bf16(A[f], Bf, C, 0, 0, 0);
    }
    float SeK = Se[T * 16 + nn];
    float sv[4];
#pragma unroll
    for (int r = 0; r < 4; r++) {
      sv[r] = fmaf(-2.f, C[r], SeK);  // token = quad*4+r, code = nn
      ml[r] = fminf(ml[r], sv[r]);
    }
    if ((c & 1) == 0) refresh();  // stale thr >= true min: superset, no miss

    bool pr[4];
#pragma unroll
    for (int r = 0; r < 4; r++) pr[r] = sv[r] < th[r] + MARGIN;
    if (__ballot(pr[0] | pr[1] | pr[2] | pr[3])) {
#pragma unroll
      for (int r = 0; r < 4; r++) {
        unsigned long long bl = __ballot(pr[r]);
        unsigned grp = (unsigned)((bl >> (quad * 16)) & 0xffffULL);
        if (grp) {
          int t = quad * 4 + r;
          int base = 0;
          if (nn == 0) base = atomicAdd(&cnt[t], __popc(grp));
          base = __shfl(base, quad * 16, 64);
          if (pr[r]) {
            int pos = base + __popc(grp & ((1u << nn) - 1u));
            if (pos < CAP) {
              cand[t][pos] = (unsigned short)(T * 16 + nn);
              cands[t][pos] = sv[r];
            }
          }
        }
      }
    }
  }
  refresh();  // exact quarter min
  if (nn == 0) {
#pragma unroll
    for (int r = 0; r < 4; r++) wsmin[w][quad * 4 + r] = th[r];
  }
  __syncthreads();

  // ---- Phase D: exact recheck; 8 slots per token, all z from LDS ----
  if (tid < 128) {
    int t = tid >> 3, slot = tid & 7;
    const float* zt = zl + t * ZPITCH;
    // Sz in exact numpy pairwise shape, slot-parallel (verified R7/R8)
    float res01[2];
#pragma unroll
    for (int blk = 0; blk < 2; blk++) {
      float v0 = zt[blk * 128 + slot];
      float rj = __fmul_rn(v0, v0);
      for (int i = 1; i < 16; i++) {
        float v = zt[blk * 128 + i * 8 + slot];
        rj = __fadd_rn(rj, __fmul_rn(v, v));
      }
      float a = __fadd_rn(rj, __shfl_down(rj, 1, 8));
      float bq = __fadd_rn(a, __shfl_down(a, 2, 8));
      res01[blk] = __fadd_rn(bq, __shfl_down(bq, 4, 8));
    }
    float Szn = __fadd_rn(res01[0], res01[1]);
    Szn = __shfl(Szn, lane & ~7, 64);  // broadcast slot0

    float amin = fminf(fminf(wsmin[0][t], wsmin[1][t]),
                       fminf(wsmin[2][t], wsmin[3][t]));
    int cc = cnt[t];
    float bD = 3.4e38f;
    int bK = 0x7fffffff;
    if (cc <= CAP) {
      for (int c = slot; c < cc; c += 8) {
        float sv = cands[t][c];
        if (sv >= amin + MARGIN) continue;  // prune stale-thr extras
        int k = cand[t][c];
        const float* er = e + (size_t)k * DIM;
        float acc = 0.f;
        for (int d = 0; d < DIM; d++) acc = fmaf(zt[d], er[d], acc);
        float D = __fsub_rn(__fadd_rn(Szn, Se[k]), __fmul_rn(2.f, acc));
        if (D < bD || (D == bD && k < bK)) { bD = D; bK = k; }
      }
    } else {  // overflow: exact full scan (rare, deterministic)
      for (int k = slot; k < K_CODES; k += 8) {
        const float* er = e + (size_t)k * DIM;
        float acc = 0.f;
        for (int d = 0; d < DIM; d++) acc = fmaf(zt[d], er[d], acc);
        float D = __fsub_rn(__fadd_rn(Szn, Se[k]), __fmul_rn(2.f, acc));
        if (D < bD || (D == bD && k < bK)) { bD = D; bK = k; }
      }
    }
#pragma unroll
    for (int off = 4; off > 0; off >>= 1) {  // lex-min across 8 slots
      float oD = __shfl_down(bD, off, 8);
      int oK = __shfl_down(bK, off, 8);
      if (oD < bD || (oD == bD && oK < bK)) { bD = oD; bK = oK; }
    }
    if (slot == 0) {
      mini_sh[t] = bK;
      out[O_IDX + n0 + t] = (float)bK;
    }
  }
  __syncthreads();

  // ---- stage selected codebook rows (coalesced along d) ----
#pragma unroll
  for (int i = 0; i < TOK_BLK; i++)
    el[i * ZPITCH + tid] = e[(size_t)mini_sh[i] * DIM + tid];
  __syncthreads();

  // ---- Phase E: quant store + fused loss (z from LDS) ----
  float sumsq = 0.f;
  float* op = out + (size_t)b * DIM * SPATIAL + s0;
  for (int i = 0; i < 16; i++) {
    int idx = i * 256 + tid;  // 4096 elements
    int d = idx >> 4, t2 = idx & 15;
    float v = el[t2 * ZPITCH + d];
    float zv = zl[t2 * ZPITCH + d];
    float df = __fsub_rn(v, zv);
    sumsq = fmaf(df, df, sumsq);
    op[(size_t)d * SPATIAL + t2] = v;  // 64B contiguous per 16 lanes
  }
#pragma unroll
  for (int o = 32; o > 0; o >>= 1) sumsq += __shfl_down(sumsq, o, 64);
  if (lane == 0) red[w] = sumsq;
  __syncthreads();
  if (tid == 0) {
    atomicAdd(ws + WS_LOSS, red[0] + red[1] + red[2] + red[3]);
    __threadfence();  // loss add visible before counter bump
    int done = atomicAdd((int*)ws + WS_DONE_I, 1);
    if (done == N_BLOCKS - 1) {  // last block: all adds complete & visible
      __threadfence();
      float total = atomicAdd(ws + WS_LOSS, 0.f);  // read via atomic path
      out[O_LOSS] = 1.25f * total / 8388608.f;
    }
  }
}

extern "C" void kernel_launch(void* const* d_in, const int* in_sizes, int n_in,
                              void* d_out, int out_size, void* d_ws, size_t ws_size,
                              hipStream_t stream) {
  const float* z = (const float*)d_in[0];
  const float* e = (const float*)d_in[1];
  float* ws = (float*)d_ws;
  float* out = (float*)d_out;

  prep_kernel<<<K_CODES / 16, 256, 0, stream>>>(e, ws);
  main_kernel<<<N_BLOCKS, 256, 0, stream>>>(z, e, ws, out);
}

// Round 10
// 236.761 us; speedup vs baseline: 3.8816x; 1.1710x over previous
//
#include <hip/hip_runtime.h>
#include <hip/hip_bf16.h>

// VQ-VAE vector quantizer, MI355X (gfx950).
//   inputs : z (8,256,16,16,16) fp32, codebook (1024,256) fp32
//   output : quant (8,256,16,16,16) ++ idx (8,16,16,16) ++ loss (1), fp32 flat
//
// Round 10: two-pass MFMA scan (R9 was latency-bound on per-tile ballot/
// atomic/shuffle filter serialization; occupancy at its register ceiling).
//   Pass 1: pure MFMA min-scan — no branches, no cross-lane, no carried
//           scalar state -> fully pipelineable.
//   Pass 2: re-scan with FIXED thr* = min + MARGIN; append branch fires only
//           for true candidates (~1-4/token). Candidate set = fixed predicate
//           -> order-independent (stronger determinism than R9).
//   Wave = 32 tokens (2 A-groups) x one code quarter -> B L2 traffic stays
//   1 GB total despite two passes; 2 MFMA per B-fragment.
//   Recheck: verified exact np-fp32 pipeline D = fl(fl(Sz+Se)-2*dot),
//   dot = ascending-d fp32 FMA chain, Sz/Se numpy pairwise order, lex-min
//   (D,k) == np.argmin first occurrence; overflow(>CAP) -> exact full scan.
//   Loss fused via device-scope done-counter (verified R8/R9).

#define K_CODES 1024
#define DIM 256
#define N_TOK 32768
#define SPATIAL 4096
#define TOK_BLK 32
#define CAP 32
#define MARGIN 1e-3f
#define ZPITCH 257

typedef __attribute__((ext_vector_type(8))) short short8;
typedef __attribute__((ext_vector_type(4))) float float4v;

// ws layout in floats
#define WS_LOSS 0
#define WS_DONE_I 1   // int slot: completed-block counter
#define WS_E2 16      // 1024 floats: Se[k] (np pairwise)
#define WS_EB 2048    // 262144 bf16: codebook, B-fragment order

#define O_IDX (8 * DIM * SPATIAL)  // 8388608
#define O_LOSS (O_IDX + N_TOK)     // 8421376
#define N_BLOCKS (N_TOK / TOK_BLK) // 1024

__device__ __forceinline__ short f2bf(float v) {  // RTNE fp32->bf16 bits
  unsigned u = __float_as_uint(v);
  u = (u + 0x7fffu + ((u >> 16) & 1u)) >> 16;
  return (short)u;
}

// prep (verified R8/R9): coalesced fragment pack + Se (np pairwise).
// Fragment layout: element (code k, dim d): T=k>>4, nn=k&15, f=d>>5,
// q=(d>>3)&3, j=d&7 -> short off ((T*8+f)*64 + (q*16+nn))*8 + j.
__global__ __launch_bounds__(256) void prep_kernel(const float* __restrict__ e,
                                                   float* __restrict__ ws) {
  int T = blockIdx.x, tid = threadIdx.x;
#pragma unroll
  for (int ii = 0; ii < 2; ii++) {
    int idx = ii * 256 + tid;  // 512 short8 fragments per 16-code tile
    int f = idx >> 6, lane = idx & 63;
    int q = lane >> 4, nn = lane & 15;
    const float* src = e + (size_t)(T * 16 + nn) * DIM + f * 32 + q * 8;
    float4 lo = *(const float4*)src;
    float4 hi = *(const float4*)(src + 4);
    unsigned s0 = (unsigned short)f2bf(lo.x) | ((unsigned)(unsigned short)f2bf(lo.y) << 16);
    unsigned s1 = (unsigned short)f2bf(lo.z) | ((unsigned)(unsigned short)f2bf(lo.w) << 16);
    unsigned s2 = (unsigned short)f2bf(hi.x) | ((unsigned)(unsigned short)f2bf(hi.y) << 16);
    unsigned s3 = (unsigned short)f2bf(hi.z) | ((unsigned)(unsigned short)f2bf(hi.w) << 16);
    uint4 p = {s0, s1, s2, s3};
    ((uint4*)(ws + WS_EB))[(T * 8 + f) * 64 + lane] = p;  // coalesced 16B
  }
  if (tid < 128) {  // Se: 8 slots per code, np pairwise (verified)
    int c8 = tid >> 3, slot = tid & 7;
    int k = T * 16 + c8;
    const float* er = e + (size_t)k * DIM;
    float res01[2];
#pragma unroll
    for (int blk = 0; blk < 2; blk++) {
      float v0 = er[blk * 128 + slot];
      float rj = __fmul_rn(v0, v0);
      for (int i = 1; i < 16; i++) {
        float v = er[blk * 128 + i * 8 + slot];
        rj = __fadd_rn(rj, __fmul_rn(v, v));
      }
      float a = __fadd_rn(rj, __shfl_down(rj, 1, 8));
      float bq = __fadd_rn(a, __shfl_down(a, 2, 8));
      res01[blk] = __fadd_rn(bq, __shfl_down(bq, 4, 8));  // valid on slot 0
    }
    if (slot == 0) ws[WS_E2 + k] = __fadd_rn(res01[0], res01[1]);
  }
  if (T == 0 && tid == 0) {
    ws[WS_LOSS] = 0.f;
    ((int*)ws)[WS_DONE_I] = 0;
  }
}

__global__ __launch_bounds__(256, 2) void main_kernel(const float* __restrict__ z,
                                                      const float* __restrict__ e,
                                                      float* __restrict__ ws,
                                                      float* __restrict__ out) {
  __shared__ float zl[TOK_BLK * ZPITCH];  // 32.9 KB: z-tile [tok][d]
  __shared__ unsigned short cand[TOK_BLK][CAP];
  __shared__ int cnt[TOK_BLK];
  __shared__ float wsmin[4][TOK_BLK];
  __shared__ float thrS[TOK_BLK];
  __shared__ int mini_sh[TOK_BLK];
  __shared__ float red[4];

  int tid = threadIdx.x, w = tid >> 6, lane = tid & 63;
  int quad = lane >> 4, nn = lane & 15;
  int n0 = blockIdx.x * TOK_BLK;
  int b = n0 >> 12, s0 = n0 & 4095;
  const float* zb = z + (size_t)b * DIM * SPATIAL + s0;
  const float* Se = ws + WS_E2;

  if (tid < TOK_BLK) cnt[tid] = 0;

  // ---- stage z-tile once: float4 global loads -> zl[t][d] ----
#pragma unroll
  for (int i = 0; i < 8; i++) {
    int idx = i * 256 + tid;  // 2048 float4 groups: d = idx>>3, g = idx&7
    int d = idx >> 3, g = idx & 7;
    float4 v = *(const float4*)(zb + (size_t)d * SPATIAL + g * 4);
    zl[(4 * g + 0) * ZPITCH + d] = v.x;
    zl[(4 * g + 1) * ZPITCH + d] = v.y;
    zl[(4 * g + 2) * ZPITCH + d] = v.z;
    zl[(4 * g + 3) * ZPITCH + d] = v.w;
  }
  __syncthreads();  // zl ready; cnt=0 visible

  // ---- A fragments (z -> bf16) from LDS, 2 groups of 16 tokens ----
  short8 A0[8], A1[8];
#pragma unroll
  for (int f = 0; f < 8; f++) {
    short8 a0, a1;
#pragma unroll
    for (int j = 0; j < 8; j++) {
      int d = f * 32 + quad * 8 + j;
      a0[j] = f2bf(zl[nn * ZPITCH + d]);
      a1[j] = f2bf(zl[(16 + nn) * ZPITCH + d]);
    }
    A0[f] = a0;
    A1[f] = a1;
  }

  const short8* eB8 = (const short8*)(ws + WS_EB);

  // ---- Pass 1: pure MFMA min-scan (wave w: codes w*256..+255) ----
  float ml0[4] = {3.4e38f, 3.4e38f, 3.4e38f, 3.4e38f};
  float ml1[4] = {3.4e38f, 3.4e38f, 3.4e38f, 3.4e38f};
  for (int c = 0; c < 16; c++) {
    int T = w * 16 + c;  // k = T*16 + nn
    float4v C0 = {0.f, 0.f, 0.f, 0.f}, C1 = {0.f, 0.f, 0.f, 0.f};
#pragma unroll
    for (int f = 0; f < 8; f++) {
      short8 Bf = eB8[(size_t)(T * 8 + f) * 64 + lane];  // L2-resident
      C0 = __builtin_amdgcn_mfma_f32_16x16x32_bf16(A0[f], Bf, C0, 0, 0, 0);
      C1 = __builtin_amdgcn_mfma_f32_16x16x32_bf16(A1[f], Bf, C1, 0, 0, 0);
    }
    float SeK = Se[T * 16 + nn];
#pragma unroll
    for (int r = 0; r < 4; r++) {
      ml0[r] = fminf(ml0[r], fmaf(-2.f, C0[r], SeK));
      ml1[r] = fminf(ml1[r], fmaf(-2.f, C1[r], SeK));
    }
  }
  // cross-lane per-token quarter min -> wsmin
#pragma unroll
  for (int r = 0; r < 4; r++) {
    float m0 = ml0[r], m1 = ml1[r];
    m0 = fminf(m0, __shfl_xor(m0, 1, 16));
    m0 = fminf(m0, __shfl_xor(m0, 2, 16));
    m0 = fminf(m0, __shfl_xor(m0, 4, 16));
    m0 = fminf(m0, __shfl_xor(m0, 8, 16));
    m1 = fminf(m1, __shfl_xor(m1, 1, 16));
    m1 = fminf(m1, __shfl_xor(m1, 2, 16));
    m1 = fminf(m1, __shfl_xor(m1, 4, 16));
    m1 = fminf(m1, __shfl_xor(m1, 8, 16));
    if (nn == 0) {
      wsmin[w][quad * 4 + r] = m0;
      wsmin[w][16 + quad * 4 + r] = m1;
    }
  }
  __syncthreads();
  if (tid < TOK_BLK)
    thrS[tid] = fminf(fminf(wsmin[0][tid], wsmin[1][tid]),
                      fminf(wsmin[2][tid], wsmin[3][tid])) + MARGIN;
  __syncthreads();

  float thr0[4], thr1[4];
#pragma unroll
  for (int r = 0; r < 4; r++) {
    thr0[r] = thrS[quad * 4 + r];
    thr1[r] = thrS[16 + quad * 4 + r];
  }

  // ---- Pass 2: fixed-threshold append (branch fires ~1-4x/token total) ----
  for (int c = 0; c < 16; c++) {
    int T = w * 16 + c;
    float4v C0 = {0.f, 0.f, 0.f, 0.f}, C1 = {0.f, 0.f, 0.f, 0.f};
#pragma unroll
    for (int f = 0; f < 8; f++) {
      short8 Bf = eB8[(size_t)(T * 8 + f) * 64 + lane];
      C0 = __builtin_amdgcn_mfma_f32_16x16x32_bf16(A0[f], Bf, C0, 0, 0, 0);
      C1 = __builtin_amdgcn_mfma_f32_16x16x32_bf16(A1[f], Bf, C1, 0, 0, 0);
    }
    float SeK = Se[T * 16 + nn];
    bool p0[4], p1[4];
#pragma unroll
    for (int r = 0; r < 4; r++) {
      p0[r] = fmaf(-2.f, C0[r], SeK) < thr0[r];
      p1[r] = fmaf(-2.f, C1[r], SeK) < thr1[r];
    }
    if (__ballot(p0[0] | p0[1] | p0[2] | p0[3] | p1[0] | p1[1] | p1[2] | p1[3])) {
#pragma unroll
      for (int g = 0; g < 2; g++) {
#pragma unroll
        for (int r = 0; r < 4; r++) {
          bool pr = g ? p1[r] : p0[r];
          unsigned long long bl = __ballot(pr);
          unsigned grp = (unsigned)((bl >> (quad * 16)) & 0xffffULL);
          if (grp) {
            int t = g * 16 + quad * 4 + r;
            int base = 0;
            if (nn == 0) base = atomicAdd(&cnt[t], __popc(grp));
            base = __shfl(base, quad * 16, 64);
            if (pr) {
              int pos = base + __popc(grp & ((1u << nn) - 1u));
              if (pos < CAP) cand[t][pos] = (unsigned short)(T * 16 + nn);
            }
          }
        }
      }
    }
  }
  __syncthreads();

  // ---- Recheck: 32 tokens x 8 slots; exact np-fp32 pipeline (verified) ----
  {
    int t = tid >> 3, slot = tid & 7;
    const float* zt = zl + t * ZPITCH;
    float res01[2];  // Sz in exact numpy pairwise shape, slot-parallel
#pragma unroll
    for (int blk = 0; blk < 2; blk++) {
      float v0 = zt[blk * 128 + slot];
      float rj = __fmul_rn(v0, v0);
      for (int i = 1; i < 16; i++) {
        float v = zt[blk * 128 + i * 8 + slot];
        rj = __fadd_rn(rj, __fmul_rn(v, v));
      }
      float a = __fadd_rn(rj, __shfl_down(rj, 1, 8));
      float bq = __fadd_rn(a, __shfl_down(a, 2, 8));
      res01[blk] = __fadd_rn(bq, __shfl_down(bq, 4, 8));
    }
    float Szn = __fadd_rn(res01[0], res01[1]);
    Szn = __shfl(Szn, lane & ~7, 64);  // broadcast slot0

    int cc = cnt[t];
    float bD = 3.4e38f;
    int bK = 0x7fffffff;
    if (cc <= CAP) {
      for (int c = slot; c < cc; c += 8) {
        int k = cand[t][c];
        const float* er = e + (size_t)k * DIM;
        float acc = 0.f;
        for (int d = 0; d < DIM; d++) acc = fmaf(zt[d], er[d], acc);
        float D = __fsub_rn(__fadd_rn(Szn, Se[k]), __fmul_rn(2.f, acc));
        if (D < bD || (D == bD && k < bK)) { bD = D; bK = k; }
      }
    } else {  // overflow: exact full scan (rare, deterministic)
      for (int k = slot; k < K_CODES; k += 8) {
        const float* er = e + (size_t)k * DIM;
        float acc = 0.f;
        for (int d = 0; d < DIM; d++) acc = fmaf(zt[d], er[d], acc);
        float D = __fsub_rn(__fadd_rn(Szn, Se[k]), __fmul_rn(2.f, acc));
        if (D < bD || (D == bD && k < bK)) { bD = D; bK = k; }
      }
    }
#pragma unroll
    for (int off = 4; off > 0; off >>= 1) {  // lex-min across 8 slots
      float oD = __shfl_down(bD, off, 8);
      int oK = __shfl_down(bK, off, 8);
      if (oD < bD || (oD == bD && oK < bK)) { bD = oD; bK = oK; }
    }
    if (slot == 0) {
      mini_sh[t] = bK;
      out[O_IDX + n0 + t] = (float)bK;
    }
  }
  __syncthreads();

  // ---- Epilogue: quant store (e rows direct from L2) + fused loss ----
  float sumsq = 0.f;
  float* op = out + (size_t)b * DIM * SPATIAL + s0;
  for (int i = 0; i < 32; i++) {
    int idx = i * 256 + tid;  // 8192 elements
    int d = idx >> 5, t2 = idx & 31;
    float v = e[(size_t)mini_sh[t2] * DIM + d];
    float zv = zl[t2 * ZPITCH + d];
    float df = __fsub_rn(v, zv);
    sumsq = fmaf(df, df, sumsq);
    op[(size_t)d * SPATIAL + t2] = v;  // 128 B contiguous per 32 lanes
  }
#pragma unroll
  for (int o = 32; o > 0; o >>= 1) sumsq += __shfl_down(sumsq, o, 64);
  if (lane == 0) red[w] = sumsq;
  __syncthreads();
  if (tid == 0) {
    atomicAdd(ws + WS_LOSS, red[0] + red[1] + red[2] + red[3]);
    __threadfence();  // loss add visible before counter bump
    int done = atomicAdd((int*)ws + WS_DONE_I, 1);
    if (done == N_BLOCKS - 1) {  // last block: all adds complete & visible
      __threadfence();
      float total = atomicAdd(ws + WS_LOSS, 0.f);  // read via atomic path
      out[O_LOSS] = 1.25f * total / 8388608.f;
    }
  }
}

extern "C" void kernel_launch(void* const* d_in, const int* in_sizes, int n_in,
                              void* d_out, int out_size, void* d_ws, size_t ws_size,
                              hipStream_t stream) {
  const float* z = (const float*)d_in[0];
  const float* e = (const float*)d_in[1];
  float* ws = (float*)d_ws;
  float* out = (float*)d_out;

  prep_kernel<<<K_CODES / 16, 256, 0, stream>>>(e, ws);
  main_kernel<<<N_BLOCKS, 256, 0, stream>>>(z, e, ws, out);
}